// Round 8
// baseline (116.985 us; speedup 1.0000x reference)
//
#include <hip/hip_runtime.h>
#include <math.h>

#define N_SETS 4096
#define SETS_PER_BLOCK 4
#define GRID_MAIN (N_SETS / SETS_PER_BLOCK)   // 1024 blocks

typedef _Float16 f16;
typedef __attribute__((ext_vector_type(8))) _Float16 f16x8;
typedef __attribute__((ext_vector_type(4))) _Float16 f16x4;
typedef __attribute__((ext_vector_type(4))) float     f32x4;

// ---------------- ws layout ----------------
#define WS_PE    0         // fp32 [64][256]  65536
#define WS_QH    65536     // f16  [64][32]   4096
#define WS_WKV   69632     // f16  [64][256]  32768  (rows 0-31 Wk, 32-63 Wv)
#define WS_WMAPH 102400    // f16  [256][32]  16384
#define WS_PEH   118784    // f16  [64][256]  32768
#define WS_PTR   151552    // int  [4097]

// aux1: blocks [0,768) -> batch_ptr + out2 echo; blocks [768,832) -> pe table
__global__ void k_aux1(const int* __restrict__ batch, float* __restrict__ out2,
                       int* __restrict__ ptr, int N, float* __restrict__ pe) {
    int blk = blockIdx.x;
    if (blk < 768) {
        int i = blk * 256 + threadIdx.x;
        if (i >= N) return;
        int b = batch[i];
        out2[i] = (float)b;
        if (i == 0 || batch[i - 1] != b) ptr[b] = i;
        if (i == N - 1) ptr[N_SETS] = N;
    } else {
        int idx = (blk - 768) * 256 + threadIdx.x;   // 0..16383
        int p = idx >> 8, i = idx & 255;
        float e   = (float)(2 * (i / 2)) / 256.0f;
        float inv = powf(10000.0f, -e);
        float ang = (float)p * inv;
        pe[idx] = (i & 1) ? cosf(ang) : sinf(ang);
    }
}

// aux2: [0,96) weight f16 convert; [96,160) peh convert; [160,168) qh
__global__ void k_aux2(const float* __restrict__ Wk, const float* __restrict__ Wv,
                       const float* __restrict__ Wq, const float* __restrict__ Wmap,
                       const float* __restrict__ pe, f16* __restrict__ wkv,
                       f16* __restrict__ wmaph, f16* __restrict__ peh,
                       f16* __restrict__ qh) {
    int blk = blockIdx.x;
    if (blk < 96) {
        int idx = blk * 256 + threadIdx.x;           // 0..24575
        if (idx < 16384) {
            int j = idx >> 8, d = idx & 255;
            float v = (j < 32) ? Wk[j * 256 + d] : Wv[(j - 32) * 256 + d];
            wkv[idx] = (f16)v;
        } else {
            int i2 = idx - 16384;
            wmaph[i2] = (f16)Wmap[i2];
        }
    } else if (blk < 160) {
        int idx = (blk - 96) * 256 + threadIdx.x;    // 0..16383
        peh[idx] = (f16)pe[idx];
    } else {
        int idx = (blk - 160) * 256 + threadIdx.x;   // 0..2047
        int pos = idx >> 5, k = idx & 31;
        const float* pr = pe + pos * 256;
        const float* wr = Wq + k * 256;
        float s = 0.f;
        for (int d = 0; d < 256; d += 4) {
            float4 a = *(const float4*)(pr + d);
            float4 b = *(const float4*)(wr + d);
            s += a.x * b.x + a.y * b.y + a.z * b.z + a.w * b.w;
        }
        qh[idx] = (f16)s;
    }
}

// Phase-batched fused encoder+decoder. 4 sets/block, 4 waves, 256 thr.
// Pipeline: G1(s0) | bar | {G2(s_{j-1}) || G1(s_j)} bar  x3 | G2(s3) | bar |
// decode all 4 sets barrier-free (row-split G4: dsh same-wave).
// 6 barriers/block (vs 16 in r7).
// LDS map (77824 B -> 2 blocks/CU; VGPR free up to ~200 since LDS binds):
//   [0,     32768)  wsh f16 [64][256] swz ((j&7)<<4)  (Wk 0-31, Wv 32-63)
//   [32768, 49152)  wmh f16 [256][32] swz ((d&7)<<4)
//   [49152, 65536)  ysh ping-pong 2 x (f16 [64c][64r] swz ((c&7)<<4))
//   [65536, 73728)  zT  4 x (f16 [32c][32r] swz ((c&3)<<4))
//   [73728, 77824)  dsh f16 [64m][32v] swz ((m&7)<<4)  (reused across sets)
__global__ __launch_bounds__(256, 2) void k_main(
        const float* __restrict__ x,     const f16* __restrict__ wkv,
        const f16* __restrict__ wmaph,   const f16* __restrict__ qh,
        const f16* __restrict__ peh,     const float* __restrict__ bmap,
        const int* __restrict__ ptr,     float* __restrict__ out) {
    __shared__ char lds[77824];
    char* wmh  = lds + 32768;
    char* dsh  = lds + 73728;

    const int t    = threadIdx.x;
    const int wv   = t >> 6;
    const int l15  = t & 15;
    const int lhi  = (t & 63) >> 4;       // 0..3
    const int arow = 16 * wv + l15;
    const int swz7 = (l15 & 7) << 4;

    int pv[SETS_PER_BLOCK + 1];
    #pragma unroll
    for (int i = 0; i <= SETS_PER_BLOCK; ++i)
        pv[i] = ptr[blockIdx.x * SETS_PER_BLOCK + i];

    // ---- stage wsh (Wk|Wv) ----
    #pragma unroll
    for (int i2 = 0; i2 < 8; ++i2) {
        int c = t + 256 * i2;
        int j = c >> 5, d0 = (c & 31) * 8;
        *(f16x8*)(lds + ((j * 512 + d0 * 2) ^ ((j & 7) << 4))) =
            *(const f16x8*)(wkv + j * 256 + d0);
    }
    // ---- stage wmh ----
    #pragma unroll
    for (int i2 = 0; i2 < 4; ++i2) {
        int c = t + 256 * i2;
        int d = c >> 2, v0 = (c & 3) * 8;
        *(f16x8*)(wmh + ((d * 64 + v0 * 2) ^ ((d & 7) << 4))) =
            *(const f16x8*)(wmaph + d * 32 + v0);
    }
    // ---- per-lane set-invariant registers ----
    f16x8 pef[8];
    #pragma unroll
    for (int ks = 0; ks < 8; ++ks)
        pef[ks] = *(const f16x8*)(peh + arow * 256 + ks * 32 + lhi * 8);
    const f16x8 qreg = *(const f16x8*)(qh + arow * 32 + lhi * 8);
    float bm[16];
    #pragma unroll
    for (int nt = 0; nt < 16; ++nt) bm[nt] = bmap[16 * nt + l15];

    // ---- full prefetch of set 0's x rows ----
    float4 xf[16];
    {
        const int s0 = pv[0], n0 = pv[1] - pv[0];
        if (arow < n0) {
            const float* xr = x + (size_t)(s0 + arow) * 256 + lhi * 8;
            #pragma unroll
            for (int ks = 0; ks < 8; ++ks) {
                xf[2 * ks]     = *(const float4*)(xr + ks * 32);
                xf[2 * ks + 1] = *(const float4*)(xr + ks * 32 + 4);
            }
        }
    }
    __syncthreads();

    // G2 helper: Z(set jj) = YV^T*YK from ysh buffer yb -> zT slot jj
    auto gemm2 = [&](int jj, char* yb) {
        const int n2 = pv[jj + 1] - pv[jj];
        const int nks = ((n2 + 31) & ~31) >> 5;
        const int it = wv >> 1, jt = wv & 1;
        f32x4 zacc = {0.f, 0.f, 0.f, 0.f};
        const int ca = 32 + 16 * it + l15, cb = 16 * jt + l15;
        for (int ks = 0; ks < nks; ++ks) {
            const int r2 = ks * 64 + lhi * 16;
            f16x8 av = *(const f16x8*)(yb + ((ca * 128 + r2) ^ swz7));
            f16x8 bk = *(const f16x8*)(yb + ((cb * 128 + r2) ^ swz7));
            zacc = __builtin_amdgcn_mfma_f32_16x16x32_f16(av, bk, zacc, 0, 0, 0);
        }
        const int zc = 16 * jt + l15, zr0 = 16 * it + lhi * 4;
        f16x4 h4;
        #pragma unroll
        for (int q = 0; q < 4; ++q) h4[q] = (f16)zacc[q];
        *(f16x4*)(lds + 65536 + jj * 2048 + ((zc * 64 + zr0 * 2) ^ ((l15 & 3) << 4))) = h4;
    };

    // ---- pipelined encoder: G1(s_j) overlaps G2(s_{j-1}) ----
    #pragma unroll
    for (int j = 0; j < SETS_PER_BLOCK; ++j) {
        char* ycur = lds + 49152 + (j & 1) * 8192;
        if (j > 0) gemm2(j - 1, lds + 49152 + ((j - 1) & 1) * 8192);

        const int s = pv[j], n = pv[j + 1] - s;
        const int n32 = (n + 31) & ~31;

        // convert current x + PE -> areg (f16)
        f16x8 areg[8];
        if (arow < n) {
            #pragma unroll
            for (int ks = 0; ks < 8; ++ks) {
                float4 a = xf[2 * ks], a2 = xf[2 * ks + 1];
                f16x8 h;
                h[0]=(f16)a.x;  h[1]=(f16)a.y;  h[2]=(f16)a.z;  h[3]=(f16)a.w;
                h[4]=(f16)a2.x; h[5]=(f16)a2.y; h[6]=(f16)a2.z; h[7]=(f16)a2.w;
                areg[ks] = h + pef[ks];
            }
        } else {
            #pragma unroll
            for (int ks = 0; ks < 8; ++ks) {
                f16x8 h;
                #pragma unroll
                for (int ii = 0; ii < 8; ++ii) h[ii] = (f16)0.f;
                areg[ks] = h;
            }
        }
        // prefetch next set's x (in flight across the barrier, consumed next iter)
        if (j + 1 < SETS_PER_BLOCK) {
            const int s1 = pv[j + 1], n1 = pv[j + 2] - pv[j + 1];
            if (arow < n1) {
                const float* xr1 = x + (size_t)(s1 + arow) * 256 + lhi * 8;
                #pragma unroll
                for (int ks = 0; ks < 8; ++ks) {
                    xf[2 * ks]     = *(const float4*)(xr1 + ks * 32);
                    xf[2 * ks + 1] = *(const float4*)(xr1 + ks * 32 + 4);
                }
            }
        }

        // ---- GEMM1: Y = (X+PE)*Wkv^T -> ycur (transposed) ----
        if (16 * wv < n32) {
            f32x4 acc[4];
            #pragma unroll
            for (int nt = 0; nt < 4; ++nt) acc[nt] = (f32x4){0.f, 0.f, 0.f, 0.f};
            #pragma unroll
            for (int ks = 0; ks < 8; ++ks) {
                #pragma unroll
                for (int nt = 0; nt < 4; ++nt) {
                    f16x8 bf = *(const f16x8*)(lds +
                        (((16 * nt + l15) * 512 + ks * 64 + lhi * 16) ^ swz7));
                    acc[nt] = __builtin_amdgcn_mfma_f32_16x16x32_f16(areg[ks], bf, acc[nt], 0, 0, 0);
                }
            }
            const int row0 = 16 * wv + lhi * 4;
            #pragma unroll
            for (int nt = 0; nt < 4; ++nt) {
                const int col = 16 * nt + l15;
                f16x4 h4;
                #pragma unroll
                for (int q = 0; q < 4; ++q) h4[q] = (f16)acc[nt][q];
                *(f16x4*)(ycur + ((col * 128 + row0 * 2) ^ swz7)) = h4;
            }
        }
        __syncthreads();
    }
    gemm2(SETS_PER_BLOCK - 1, lds + 49152 + ((SETS_PER_BLOCK - 1) & 1) * 8192);
    __syncthreads();

    // ---- decode all 4 sets, barrier-free ----
    #pragma unroll
    for (int j = 0; j < SETS_PER_BLOCK; ++j) {
        const int s = pv[j], n = pv[j + 1] - s;
        if (16 * wv >= n) continue;
        char* zsh = lds + 65536 + j * 2048;
        const int k2 = lhi * 16;

        // GEMM3: dec = query * Z -> dsh (own-wave rows)
        {
            f16x8 bz0 = *(const f16x8*)(zsh + ((l15 * 64 + k2) ^ ((l15 & 3) << 4)));
            f16x8 bz1 = *(const f16x8*)(zsh + (((16 + l15) * 64 + k2) ^ ((l15 & 3) << 4)));
            f32x4 dd0 = {0.f, 0.f, 0.f, 0.f}, dd1 = {0.f, 0.f, 0.f, 0.f};
            dd0 = __builtin_amdgcn_mfma_f32_16x16x32_f16(qreg, bz0, dd0, 0, 0, 0);
            dd1 = __builtin_amdgcn_mfma_f32_16x16x32_f16(qreg, bz1, dd1, 0, 0, 0);
            #pragma unroll
            for (int q = 0; q < 4; ++q) {
                const int m = 16 * wv + lhi * 4 + q;
                *(f16*)(dsh + ((m * 64 + l15 * 2) ^ ((m & 7) << 4)))        = (f16)dd0[q];
                *(f16*)(dsh + ((m * 64 + (16 + l15) * 2) ^ ((m & 7) << 4))) = (f16)dd1[q];
            }
        }
        // GEMM4 (row-split): out rows 16wv.. = dec * Wmap^T + bmap (same-wave dsh)
        {
            f16x8 ad = *(const f16x8*)(dsh + (((16 * wv + l15) * 64 + k2) ^ swz7));
            const int row0 = 16 * wv + lhi * 4;
            float* ob = out + (size_t)s * 256;
            #pragma unroll
            for (int nt = 0; nt < 16; ++nt) {
                const int dcol = 16 * nt + l15;
                f16x8 bw = *(const f16x8*)(wmh + ((dcol * 64 + k2) ^ swz7));
                f32x4 o = {0.f, 0.f, 0.f, 0.f};
                o = __builtin_amdgcn_mfma_f32_16x16x32_f16(ad, bw, o, 0, 0, 0);
                #pragma unroll
                for (int q = 0; q < 4; ++q)
                    ob[(size_t)(row0 + q) * 256 + dcol] = o[q] + bm[nt];
            }
        }
    }
}

extern "C" void kernel_launch(void* const* d_in, const int* in_sizes, int n_in,
                              void* d_out, int out_size, void* d_ws, size_t ws_size,
                              hipStream_t stream) {
    const float* x    = (const float*)d_in[0];
    const int*   batch= (const int*)  d_in[1];
    const float* Wk   = (const float*)d_in[2];
    const float* Wv   = (const float*)d_in[3];
    const float* Wq   = (const float*)d_in[4];
    const float* Wmap = (const float*)d_in[5];
    const float* bmap = (const float*)d_in[6];
    float* out = (float*)d_out;

    const int N = in_sizes[1];                 // 196608 rows
    float* pe    = (float*)((char*)d_ws + WS_PE);
    f16*   qh    = (f16*)  ((char*)d_ws + WS_QH);
    f16*   wkv   = (f16*)  ((char*)d_ws + WS_WKV);
    f16*   wmaph = (f16*)  ((char*)d_ws + WS_WMAPH);
    f16*   peh   = (f16*)  ((char*)d_ws + WS_PEH);
    int*   ptr   = (int*)  ((char*)d_ws + WS_PTR);
    float* out2  = out + (size_t)N * 256;      // output 1: batch echo as floats

    k_aux1<<<832, 256, 0, stream>>>(batch, out2, ptr, N, pe);
    k_aux2<<<168, 256, 0, stream>>>(Wk, Wv, Wq, Wmap, pe, wkv, wmaph, peh, qh);
    k_main<<<GRID_MAIN, 256, 0, stream>>>(x, wkv, wmaph, qh, peh, bmap, ptr, out);
}